// Round 12
// baseline (198.575 us; speedup 1.0000x reference)
//
#include <hip/hip_runtime.h>
#include <cstdint>
#include <cstddef>

#define B_ 8
#define N_ 2048
#define D_ 2048
#define E_ 64
#define CAP_ 64
#define NTOK (B_*N_)                  // 16384 tokens
#define GEMM_BLOCKS 256               // 64 tokens/block, 4 waves
#define WCONV_BLOCKS 64
#define FILL_BLOCKS 4096              // 128 KB contiguous per block, exact division
#define DC 64                         // d-tile
#define NTILE (D_/DC)                 // 32
#define MASK_ELEMS ((size_t)NTOK*(size_t)E_*(size_t)CAP_)   // 67108864 per output

typedef float f32x4 __attribute__((ext_vector_type(4)));
typedef short bf16x8 __attribute__((ext_vector_type(8)));
typedef unsigned int u32;
typedef u32 u32x2 __attribute__((ext_vector_type(2)));

__device__ __forceinline__ u32 f2bf(float f) {          // RNE f32 -> bf16 bits
  u32 u = __float_as_uint(f);
  return (u + 0x7fffu + ((u >> 16) & 1u)) >> 16;
}
__device__ __forceinline__ float bf2f(u32 b) { return __uint_as_float(b << 16); }

// K_A: fused W-convert (blocks 0..63) + pure zero-fill (blocks 64..4159).
// ZERO LDS -> fill runs at full occupancy (32 waves/CU), rocclr-style plain
// stores: contiguous 128 KB span per block, 4 x dwordx4 at immediate offsets.
__global__ __launch_bounds__(256)
void k_fill_wconv(const float* __restrict__ W, u32* __restrict__ whi,
                  u32* __restrict__ wlo, float* __restrict__ out) {
  const int bid = blockIdx.x;
  const int tid = threadIdx.x;
  if (bid < WCONV_BLOCKS) {
    // W[2048][64] f32 -> WhiT/WloT bf16, transposed to [e][d], tile-swizzled:
    // granule (t*64+e)*8 + (g^(e&7)) holds d = t*64+g*8..+7 of expert e.
    const int i = bid * 256 + tid;                  // 16384 = (t,e,g)
    const int g = i & 7, e = (i >> 3) & 63, t = i >> 9;
    const int d0 = t * DC + g * 8;
    const int dst = ((t * 64 + e) * 8 + (g ^ (e & 7))) * 4;  // in u32
    #pragma unroll
    for (int jj = 0; jj < 4; ++jj) {
      const float x0 = W[(size_t)(d0 + 2*jj    ) * E_ + e];
      const float x1 = W[(size_t)(d0 + 2*jj + 1) * E_ + e];
      const u32 h0 = f2bf(x0), h1 = f2bf(x1);
      const u32 l0 = f2bf(x0 - bf2f(h0)), l1 = f2bf(x1 - bf2f(h1));
      whi[dst + jj] = h0 | (h1 << 16);
      wlo[dst + jj] = l0 | (l1 << 16);
    }
    return;
  }
  // ---- zero-fill: dispatch_mask + combine_array (+ z slot) ----
  const int zb   = bid - WCONV_BLOCKS;              // 0..4095
  const int wid  = tid >> 6, lane = tid & 63;
  const f32x4 z4 = {0.f, 0.f, 0.f, 0.f};
  f32x4* p = (f32x4*)out + ((size_t)zb*8192 + wid*256 + lane);
  #pragma unroll
  for (int j = 0; j < 8; ++j) {                     // 8 x 16KB chunks per block
    p[  0] = z4;
    p[ 64] = z4;
    p[128] = z4;
    p[192] = z4;
    p += 1024;
  }
  if (zb == 0 && tid == 0) out[2*MASK_ELEMS] = 0.f; // z-loss slot
}

// K_B: split-bf16 MFMA logits GEMM + per-token softmax stats (R7 branch verbatim).
__global__ __launch_bounds__(256)
void k_gemm(const float* __restrict__ X, const u32* __restrict__ whi,
            const u32* __restrict__ wlo, float* __restrict__ gate_ws,
            int* __restrict__ idx_ws, float* __restrict__ z_ws) {
  const int bid = blockIdx.x;
  // buf layout per 32KB half: XH 0 | XL 8192 | WH 16384 | WL 24576
  __shared__ __align__(16) char lds[2][32768];
  const int tid  = threadIdx.x;
  const int lane = tid & 63;
  const int wid  = __builtin_amdgcn_readfirstlane(tid >> 6);
  const int tokbase = bid * 64;
  const int woff = wid * 16;            // wave's 16-token panel
  const int rA = lane & 15, kg = lane >> 4;

  // X staging map: p in 0..3 -> chunk c = p*256+tid ; row r=c>>4, f32x4-col q=c&15
  int xr_r[4], xr_q[4], xw_off[4];
  #pragma unroll
  for (int p = 0; p < 4; ++p) {
    const int c = p*256 + tid;
    const int r = c >> 4, q = c & 15;
    xr_r[p] = r; xr_q[p] = q;
    xw_off[p] = r*128 + (((q >> 1) ^ (r & 7)) << 4) + ((q & 1) << 3);
  }
  const f32x4* xg   = (const f32x4*)X;
  const f32x4* whi4 = (const f32x4*)whi;
  const f32x4* wlo4 = (const f32x4*)wlo;

  f32x4 xr[4], wr[4];

#define XW_LOAD(t)                                                            \
  { _Pragma("unroll")                                                         \
    for (int p = 0; p < 4; ++p)                                               \
      xr[p] = xg[(size_t)(tokbase + xr_r[p])*512 + (size_t)(t)*16 + xr_q[p]]; \
    wr[0] = whi4[(size_t)(t)*512 + tid];                                      \
    wr[1] = whi4[(size_t)(t)*512 + 256 + tid];                                \
    wr[2] = wlo4[(size_t)(t)*512 + tid];                                      \
    wr[3] = wlo4[(size_t)(t)*512 + 256 + tid]; }

#define XW_STORE(buf)                                                         \
  { char* bq = lds[buf];                                                      \
    _Pragma("unroll")                                                         \
    for (int p = 0; p < 4; ++p) {                                             \
      const u32 h0 = f2bf(xr[p][0]), h1 = f2bf(xr[p][1]);                     \
      const u32 h2 = f2bf(xr[p][2]), h3 = f2bf(xr[p][3]);                     \
      const u32 l0 = f2bf(xr[p][0] - bf2f(h0)), l1 = f2bf(xr[p][1] - bf2f(h1)); \
      const u32 l2 = f2bf(xr[p][2] - bf2f(h2)), l3 = f2bf(xr[p][3] - bf2f(h3)); \
      u32x2 hp; hp[0] = h0 | (h1 << 16); hp[1] = h2 | (h3 << 16);             \
      u32x2 lp; lp[0] = l0 | (l1 << 16); lp[1] = l2 | (l3 << 16);             \
      *(u32x2*)(bq + xw_off[p])        = hp;                                  \
      *(u32x2*)(bq + 8192 + xw_off[p]) = lp;                                  \
    }                                                                         \
    *(f32x4*)(bq + 16384 +        tid*16) = wr[0];                            \
    *(f32x4*)(bq + 16384 + 4096 + tid*16) = wr[1];                            \
    *(f32x4*)(bq + 24576 +        tid*16) = wr[2];                            \
    *(f32x4*)(bq + 24576 + 4096 + tid*16) = wr[3]; }

  XW_LOAD(0);
  XW_STORE(0);
  __syncthreads();

  f32x4 acc[4];
  #pragma unroll
  for (int eb = 0; eb < 4; ++eb) { acc[eb][0]=0.f; acc[eb][1]=0.f; acc[eb][2]=0.f; acc[eb][3]=0.f; }

  const int tokrow = woff + rA;
  for (int t = 0; t < NTILE; ++t) {
    if (t + 1 < NTILE) XW_LOAD(t + 1);

    const char* bp = lds[t & 1];
    #pragma unroll
    for (int kk = 0; kk < 2; ++kk) {
      const int gA = ((kk*4 + kg) ^ (rA & 7)) << 4;       // tokrow&7 == rA&7
      const bf16x8 Ah = *(const bf16x8*)(bp +        tokrow*128 + gA);
      const bf16x8 Al = *(const bf16x8*)(bp + 8192 + tokrow*128 + gA);
      #pragma unroll
      for (int eb = 0; eb < 4; ++eb) {
        const int e  = eb*16 + rA;
        const int gB = ((kk*4 + kg) ^ (e & 7)) << 4;
        const bf16x8 Bh = *(const bf16x8*)(bp + 16384 + e*128 + gB);
        const bf16x8 Bl = *(const bf16x8*)(bp + 24576 + e*128 + gB);
        acc[eb] = __builtin_amdgcn_mfma_f32_16x16x32_bf16(Ah, Bh, acc[eb], 0, 0, 0);
        acc[eb] = __builtin_amdgcn_mfma_f32_16x16x32_bf16(Ah, Bl, acc[eb], 0, 0, 0);
        acc[eb] = __builtin_amdgcn_mfma_f32_16x16x32_bf16(Al, Bh, acc[eb], 0, 0, 0);
        acc[eb] = __builtin_amdgcn_mfma_f32_16x16x32_bf16(Al, Bl, acc[eb], 0, 0, 0);
      }
    }

    if (t + 1 < NTILE) XW_STORE((t + 1) & 1);
    __syncthreads();
  }

  // ---- epilogue: logits -> LDS [64 tok][65], per-wave butterfly softmax ----
  float* Lg = (float*)&lds[0][0];
  // C/D layout: col = lane&15 (expert within block), row = (lane>>4)*4 + reg
  #pragma unroll
  for (int eb = 0; eb < 4; ++eb)
    #pragma unroll
    for (int r = 0; r < 4; ++r)
      Lg[(woff + kg*4 + r)*65 + eb*16 + rA] = acc[eb][r];
  __syncthreads();

  #pragma unroll 1
  for (int i = 0; i < 16; ++i) {
    const int tkn = woff + i;
    const float v = Lg[tkn*65 + lane];       // lane = expert
    float vmax = v; int vidx = lane;
    #pragma unroll
    for (int m = 1; m < 64; m <<= 1) {
      const float om = __shfl_xor(vmax, m);
      const int   oi = __shfl_xor(vidx, m);
      if (om > vmax || (om == vmax && oi < vidx)) { vmax = om; vidx = oi; }
    }
    float se = expf(v - vmax);
    #pragma unroll
    for (int m = 1; m < 64; m <<= 1) se += __shfl_xor(se, m);
    if (lane == 0) {
      const int row = tokbase + tkn;
      gate_ws[row] = 1.0f / se;              // max softmax prob
      idx_ws[row]  = vidx;                   // argmax, first occurrence
      z_ws[row]    = vmax + logf(se);        // logsumexp
    }
  }
#undef XW_LOAD
#undef XW_STORE
}

// K_C: per-batch position-in-expert cumsum via bit-sliced ballots + scatter + z-loss.
__global__ __launch_bounds__(64)
void k_route(const float* __restrict__ gate_ws, const int* __restrict__ idx_ws,
             const float* __restrict__ z_ws, float* __restrict__ out) {
  const int b    = blockIdx.x;
  const int lane = threadIdx.x;
  float* dispatch = out;
  float* combine  = out + MASK_ELEMS;

  int   cnt  = 0;
  float zsum = 0.f;
  const unsigned long long below = (1ULL << lane) - 1ULL;

  for (int n0 = 0; n0 < N_; n0 += 64) {
    const int   t    = b*N_ + n0 + lane;
    const int   idx  = idx_ws[t];
    const float gate = gate_ws[t];
    const float z    = z_ws[t];
    zsum += z * z;

    unsigned long long bb[6];
    #pragma unroll
    for (int k = 0; k < 6; ++k) bb[k] = __ballot((idx >> k) & 1);

    unsigned long long m_tok = ~0ULL, m_exp = ~0ULL;
    #pragma unroll
    for (int k = 0; k < 6; ++k) {
      m_tok &= ((idx  >> k) & 1) ? bb[k] : ~bb[k];
      m_exp &= ((lane >> k) & 1) ? bb[k] : ~bb[k];
    }

    const int rank = __popcll(m_tok & below);
    const int base = __shfl(cnt, idx);
    const int pos  = base + rank;
    cnt += __popcll(m_exp);

    if (pos < CAP_) {
      const size_t o = (((size_t)t)*E_ + (size_t)idx)*CAP_ + (size_t)pos;
      dispatch[o] = 1.0f;
      combine[o]  = gate;
    }
  }

  #pragma unroll
  for (int m = 1; m < 64; m <<= 1) zsum += __shfl_xor(zsum, m);
  if (lane == 0) atomicAdd(out + 2*MASK_ELEMS, zsum * (1.0f / (float)NTOK));
}

extern "C" void kernel_launch(void* const* d_in, const int* in_sizes, int n_in,
                              void* d_out, int out_size, void* d_ws, size_t ws_size,
                              hipStream_t stream) {
  const float* X = (const float*)d_in[0];   // [8,2048,2048]
  const float* W = (const float*)d_in[1];   // [2048,64]
  float* out = (float*)d_out;               // dispatch | combine | z_loss

  char* wsb = (char*)d_ws;
  u32*   whi     = (u32*)  (wsb);            // 256 KB
  u32*   wlo     = (u32*)  (wsb + 262144);   // 256 KB
  float* gate_ws = (float*)(wsb + 524288);   // 64 KB
  int*   idx_ws  = (int*)  (wsb + 589824);   // 64 KB
  float* z_ws    = (float*)(wsb + 655360);   // 64 KB

  hipLaunchKernelGGL(k_fill_wconv, dim3(WCONV_BLOCKS + FILL_BLOCKS), dim3(256), 0, stream,
                     W, whi, wlo, out);
  hipLaunchKernelGGL(k_gemm, dim3(GEMM_BLOCKS), dim3(256), 0, stream,
                     X, whi, wlo, gate_ws, idx_ws, z_ws);
  hipLaunchKernelGGL(k_route, dim3(B_), dim3(64), 0, stream,
                     gate_ws, idx_ws, z_ws, out);
}

// Round 13
// 132.481 us; speedup vs baseline: 1.4989x; 1.4989x over previous
//
#include <hip/hip_runtime.h>
#include <cstdint>
#include <cstddef>

#define B_ 8
#define N_ 2048
#define D_ 2048
#define E_ 64
#define CAP_ 64
#define NTOK (B_*N_)                  // 16384 tokens
#define GEMM_BLOCKS 256               // 64 tokens/block, 4 waves
#define FILL_BLOCKS 4096              // 128 KB contiguous per block, exact division
#define TOTAL_BLOCKS (GEMM_BLOCKS + FILL_BLOCKS)
#define DC 64                         // d-tile
#define NTILE (D_/DC)                 // 32
#define MASK_ELEMS ((size_t)NTOK*(size_t)E_*(size_t)CAP_)   // 67108864 per output

typedef float f32x4 __attribute__((ext_vector_type(4)));
typedef short bf16x8 __attribute__((ext_vector_type(8)));
typedef unsigned int u32;
typedef u32 u32x2 __attribute__((ext_vector_type(2)));

__device__ __forceinline__ u32 f2bf(float f) {          // RNE f32 -> bf16 bits
  u32 u = __float_as_uint(f);
  return (u + 0x7fffu + ((u >> 16) & 1u)) >> 16;
}
__device__ __forceinline__ float bf2f(u32 b) { return __uint_as_float(b << 16); }

// K0: W[2048][64] f32 -> WhiT/WloT bf16, transposed to [e][d] and tile-swizzled:
// 16B-granule index = (t*64 + e)*8 + (g ^ (e&7)), holding d = t*64+g*8..+7 of expert e.
__global__ __launch_bounds__(256)
void k_wconv(const float* __restrict__ W, u32* __restrict__ whi, u32* __restrict__ wlo) {
  const int i = blockIdx.x * 256 + threadIdx.x;   // 16384 = (t,e,g)
  const int g = i & 7, e = (i >> 3) & 63, t = i >> 9;
  const int d0 = t * DC + g * 8;
  const int dst = ((t * 64 + e) * 8 + (g ^ (e & 7))) * 4;  // in u32 (8 bf16 = 4 u32)
  #pragma unroll
  for (int jj = 0; jj < 4; ++jj) {
    const float x0 = W[(size_t)(d0 + 2*jj    ) * E_ + e];
    const float x1 = W[(size_t)(d0 + 2*jj + 1) * E_ + e];
    const u32 h0 = f2bf(x0), h1 = f2bf(x1);
    const u32 l0 = f2bf(x0 - bf2f(h0)), l1 = f2bf(x1 - bf2f(h1));
    whi[dst + jj] = h0 | (h1 << 16);
    wlo[dst + jj] = l0 | (l1 << 16);
  }
}

// K1: fused zero-fill + split-bf16 MFMA logits GEMM + per-token softmax stats.
// R7 structure; GEMM K-loop upgraded to a 2-deep register pipeline: at top of
// iter t, STORE tile t+1 (loaded one full iteration ago) and LOAD tile t+2.
__global__ __launch_bounds__(256)
void k_gemm_zero(const float* __restrict__ X, const u32* __restrict__ whi,
                 const u32* __restrict__ wlo, float* __restrict__ out,
                 float* __restrict__ gate_ws, int* __restrict__ idx_ws,
                 float* __restrict__ z_ws) {
  const int bid = blockIdx.x;
  if (bid >= GEMM_BLOCKS) {
    // ---- zero-fill: dispatch_mask + combine_array (+ z slot), R7-proven ----
    const int zb   = bid - GEMM_BLOCKS;               // 0..4095
    const int tid  = threadIdx.x;
    const int wid  = tid >> 6, lane = tid & 63;
    const f32x4 z4 = {0.f, 0.f, 0.f, 0.f};
    f32x4* p = (f32x4*)out + ((size_t)zb*8192 + wid*256 + lane);
    #pragma unroll
    for (int j = 0; j < 8; ++j) {                     // 8 x 16KB chunks per block
      __builtin_nontemporal_store(z4, p +   0);
      __builtin_nontemporal_store(z4, p +  64);
      __builtin_nontemporal_store(z4, p + 128);
      __builtin_nontemporal_store(z4, p + 192);
      p += 1024;
    }
    if (zb == 0 && tid == 0) out[2*MASK_ELEMS] = 0.f; // z-loss slot
    return;
  }

  // buf layout per 32KB half: XH 0 | XL 8192 | WH 16384 | WL 24576
  __shared__ __align__(16) char lds[2][32768];
  const int tid  = threadIdx.x;
  const int lane = tid & 63;
  const int wid  = __builtin_amdgcn_readfirstlane(tid >> 6);
  const int tokbase = bid * 64;
  const int woff = wid * 16;            // wave's 16-token panel
  const int rA = lane & 15, kg = lane >> 4;

  // X staging map: p in 0..3 -> chunk c = p*256+tid ; row r=c>>4, f32x4-col q=c&15
  int xr_r[4], xr_q[4], xw_off[4];
  #pragma unroll
  for (int p = 0; p < 4; ++p) {
    const int c = p*256 + tid;
    const int r = c >> 4, q = c & 15;
    xr_r[p] = r; xr_q[p] = q;
    xw_off[p] = r*128 + (((q >> 1) ^ (r & 7)) << 4) + ((q & 1) << 3);
  }
  const f32x4* xg   = (const f32x4*)X;
  const f32x4* whi4 = (const f32x4*)whi;
  const f32x4* wlo4 = (const f32x4*)wlo;

  // two register staging sets (A/B) for the 2-deep pipeline
  f32x4 xrA[4], wrA[4], xrB[4], wrB[4];

#define XW_LOAD(S, t)                                                         \
  { _Pragma("unroll")                                                         \
    for (int p = 0; p < 4; ++p)                                               \
      xr##S[p] = xg[(size_t)(tokbase + xr_r[p])*512 + (size_t)(t)*16 + xr_q[p]]; \
    wr##S[0] = whi4[(size_t)(t)*512 + tid];                                   \
    wr##S[1] = whi4[(size_t)(t)*512 + 256 + tid];                             \
    wr##S[2] = wlo4[(size_t)(t)*512 + tid];                                   \
    wr##S[3] = wlo4[(size_t)(t)*512 + 256 + tid]; }

#define XW_STORE(S, buf)                                                      \
  { char* bq = lds[buf];                                                      \
    _Pragma("unroll")                                                         \
    for (int p = 0; p < 4; ++p) {                                             \
      const u32 h0 = f2bf(xr##S[p][0]), h1 = f2bf(xr##S[p][1]);               \
      const u32 h2 = f2bf(xr##S[p][2]), h3 = f2bf(xr##S[p][3]);               \
      const u32 l0 = f2bf(xr##S[p][0] - bf2f(h0)), l1 = f2bf(xr##S[p][1] - bf2f(h1)); \
      const u32 l2 = f2bf(xr##S[p][2] - bf2f(h2)), l3 = f2bf(xr##S[p][3] - bf2f(h3)); \
      u32x2 hp; hp[0] = h0 | (h1 << 16); hp[1] = h2 | (h3 << 16);             \
      u32x2 lp; lp[0] = l0 | (l1 << 16); lp[1] = l2 | (l3 << 16);             \
      *(u32x2*)(bq + xw_off[p])        = hp;                                  \
      *(u32x2*)(bq + 8192 + xw_off[p]) = lp;                                  \
    }                                                                         \
    *(f32x4*)(bq + 16384 +        tid*16) = wr##S[0];                         \
    *(f32x4*)(bq + 16384 + 4096 + tid*16) = wr##S[1];                         \
    *(f32x4*)(bq + 24576 +        tid*16) = wr##S[2];                         \
    *(f32x4*)(bq + 24576 + 4096 + tid*16) = wr##S[3]; }

#define MFMA_TILE(buf)                                                        \
  { const char* bp = lds[buf];                                                \
    _Pragma("unroll")                                                         \
    for (int kk = 0; kk < 2; ++kk) {                                          \
      const int gA = ((kk*4 + kg) ^ (rA & 7)) << 4;                           \
      const bf16x8 Ah = *(const bf16x8*)(bp +        tokrow*128 + gA);        \
      const bf16x8 Al = *(const bf16x8*)(bp + 8192 + tokrow*128 + gA);        \
      _Pragma("unroll")                                                       \
      for (int eb = 0; eb < 4; ++eb) {                                        \
        const int e  = eb*16 + rA;                                            \
        const int gB = ((kk*4 + kg) ^ (e & 7)) << 4;                          \
        const bf16x8 Bh = *(const bf16x8*)(bp + 16384 + e*128 + gB);          \
        const bf16x8 Bl = *(const bf16x8*)(bp + 24576 + e*128 + gB);          \
        acc[eb] = __builtin_amdgcn_mfma_f32_16x16x32_bf16(Ah, Bh, acc[eb], 0, 0, 0); \
        acc[eb] = __builtin_amdgcn_mfma_f32_16x16x32_bf16(Ah, Bl, acc[eb], 0, 0, 0); \
        acc[eb] = __builtin_amdgcn_mfma_f32_16x16x32_bf16(Al, Bh, acc[eb], 0, 0, 0); \
        acc[eb] = __builtin_amdgcn_mfma_f32_16x16x32_bf16(Al, Bl, acc[eb], 0, 0, 0); \
      }                                                                       \
    } }

  f32x4 acc[4];
  #pragma unroll
  for (int eb = 0; eb < 4; ++eb) { acc[eb][0]=0.f; acc[eb][1]=0.f; acc[eb][2]=0.f; acc[eb][3]=0.f; }
  const int tokrow = woff + rA;

  // prologue: tile0 -> lds[0] (via A), tile1 -> regs B
  XW_LOAD(A, 0);
  XW_STORE(A, 0);
  XW_LOAD(B, 1);
  __syncthreads();

  // main loop, 2-unrolled. invariant at top of even iter t:
  //   lds[t&1] = tile t (ready); set B = tile t+1 (regs); set A free.
  for (int tt = 0; tt < NTILE; tt += 2) {
    {                                   // t = tt (even)
      const int t = tt;
      if (t + 1 < NTILE) XW_STORE(B, 1);          // tile t+1 -> lds[1]
      if (t + 2 < NTILE) XW_LOAD(A, t + 2);       // tile t+2 -> set A
      MFMA_TILE(0);                                // compute tile t
      __syncthreads();
    }
    {                                   // t = tt+1 (odd)
      const int t = tt + 1;
      if (t + 1 < NTILE) XW_STORE(A, 0);          // tile t+1 -> lds[0]
      if (t + 2 < NTILE) XW_LOAD(B, t + 2);       // tile t+2 -> set B
      MFMA_TILE(1);                                // compute tile t
      __syncthreads();
    }
  }

  // ---- epilogue: logits -> LDS [64 tok][65], per-wave butterfly softmax ----
  float* Lg = (float*)&lds[0][0];
  // C/D layout: col = lane&15 (expert within block), row = (lane>>4)*4 + reg
  #pragma unroll
  for (int eb = 0; eb < 4; ++eb)
    #pragma unroll
    for (int r = 0; r < 4; ++r)
      Lg[(woff + kg*4 + r)*65 + eb*16 + rA] = acc[eb][r];
  __syncthreads();

  #pragma unroll 1
  for (int i = 0; i < 16; ++i) {
    const int tkn = woff + i;
    const float v = Lg[tkn*65 + lane];       // lane = expert
    float vmax = v; int vidx = lane;
    #pragma unroll
    for (int m = 1; m < 64; m <<= 1) {
      const float om = __shfl_xor(vmax, m);
      const int   oi = __shfl_xor(vidx, m);
      if (om > vmax || (om == vmax && oi < vidx)) { vmax = om; vidx = oi; }
    }
    float se = expf(v - vmax);
    #pragma unroll
    for (int m = 1; m < 64; m <<= 1) se += __shfl_xor(se, m);
    if (lane == 0) {
      const int row = tokbase + tkn;
      gate_ws[row] = 1.0f / se;              // max softmax prob
      idx_ws[row]  = vidx;                   // argmax, first occurrence
      z_ws[row]    = vmax + logf(se);        // logsumexp
    }
  }
#undef XW_LOAD
#undef XW_STORE
#undef MFMA_TILE
}

// K2: per-batch position-in-expert cumsum via bit-sliced ballots + scatter + z-loss.
__global__ __launch_bounds__(64)
void k_route(const float* __restrict__ gate_ws, const int* __restrict__ idx_ws,
             const float* __restrict__ z_ws, float* __restrict__ out) {
  const int b    = blockIdx.x;
  const int lane = threadIdx.x;
  float* dispatch = out;
  float* combine  = out + MASK_ELEMS;

  int   cnt  = 0;
  float zsum = 0.f;
  const unsigned long long below = (1ULL << lane) - 1ULL;

  for (int n0 = 0; n0 < N_; n0 += 64) {
    const int   t    = b*N_ + n0 + lane;
    const int   idx  = idx_ws[t];
    const float gate = gate_ws[t];
    const float z    = z_ws[t];
    zsum += z * z;

    unsigned long long bb[6];
    #pragma unroll
    for (int k = 0; k < 6; ++k) bb[k] = __ballot((idx >> k) & 1);

    unsigned long long m_tok = ~0ULL, m_exp = ~0ULL;
    #pragma unroll
    for (int k = 0; k < 6; ++k) {
      m_tok &= ((idx  >> k) & 1) ? bb[k] : ~bb[k];
      m_exp &= ((lane >> k) & 1) ? bb[k] : ~bb[k];
    }

    const int rank = __popcll(m_tok & below);
    const int base = __shfl(cnt, idx);
    const int pos  = base + rank;
    cnt += __popcll(m_exp);

    if (pos < CAP_) {
      const size_t o = (((size_t)t)*E_ + (size_t)idx)*CAP_ + (size_t)pos;
      dispatch[o] = 1.0f;
      combine[o]  = gate;
    }
  }

  #pragma unroll
  for (int m = 1; m < 64; m <<= 1) zsum += __shfl_xor(zsum, m);
  if (lane == 0) atomicAdd(out + 2*MASK_ELEMS, zsum * (1.0f / (float)NTOK));
}

extern "C" void kernel_launch(void* const* d_in, const int* in_sizes, int n_in,
                              void* d_out, int out_size, void* d_ws, size_t ws_size,
                              hipStream_t stream) {
  const float* X = (const float*)d_in[0];   // [8,2048,2048]
  const float* W = (const float*)d_in[1];   // [2048,64]
  float* out = (float*)d_out;               // dispatch | combine | z_loss

  char* wsb = (char*)d_ws;
  u32*   whi     = (u32*)  (wsb);            // 256 KB
  u32*   wlo     = (u32*)  (wsb + 262144);   // 256 KB
  float* gate_ws = (float*)(wsb + 524288);   // 64 KB
  int*   idx_ws  = (int*)  (wsb + 589824);   // 64 KB
  float* z_ws    = (float*)(wsb + 655360);   // 64 KB

  hipLaunchKernelGGL(k_wconv, dim3(64), dim3(256), 0, stream, W, whi, wlo);
  hipLaunchKernelGGL(k_gemm_zero, dim3(TOTAL_BLOCKS), dim3(256), 0, stream,
                     X, whi, wlo, out, gate_ws, idx_ws, z_ws);
  hipLaunchKernelGGL(k_route, dim3(B_), dim3(64), 0, stream,
                     gate_ws, idx_ws, z_ws, out);
}